// Round 8
// baseline (680.203 us; speedup 1.0000x reference)
//
#include <hip/hip_runtime.h>
#include <math.h>

// Problem constants
constexpr int DD    = 512;     // D
constexpr int D2    = 1024;    // 2D
constexpr int NTOK  = 256;     // vocab V (unique tokens = unique pipelines)
constexpr int NSYM  = 512;
constexpr int NCON  = 64;
constexpr int VOCAB = 256;
constexpr int BS_TOT = 32 * 512;   // B*S = 16384
constexpr int NDEPTH = 6;
constexpr int NLOOK  = 3;
constexpr float EPSF = 1e-8f;
constexpr float SCALE = 0.044194173824159216f; // 512^-0.5

__device__ inline void fma4(float4& a, const float4& w, float s) {
    a.x += w.x * s; a.y += w.y * s; a.z += w.z * s; a.w += w.w * s;
}

__device__ inline float wave_sum(float x) {
#pragma unroll
    for (int off = 32; off; off >>= 1) x += __shfl_xor(x, off, 64);
    return x;
}

__device__ inline void wave_argmin(float& d, int& i) {
#pragma unroll
    for (int off = 32; off; off >>= 1) {
        float od = __shfl_xor(d, off, 64);
        int   oi = __shfl_xor(i, off, 64);
        if (od < d || (od == d && oi < i)) { d = od; i = oi; }
    }
}

// ---- epilogue helpers (bit-exact replicas of epikv's math) ----
__device__ inline float epi1(float lr, float li, bool hi) {
    float m = sqrtf(lr * lr + li * li + EPSF);
    float inv = 1.0f / (1.0f + m);
    return tanhf((hi ? li : lr) * inv);
}

// combine NS split-K partials for the float4 of z at (t, k4..k4+3)
__device__ inline float4 epi_load(const float* __restrict__ P, int NS, int t, int k4) {
    int jr = k4 & 511;
    bool hi = (k4 & 512) != 0;
    float4 lr = {0.f,0.f,0.f,0.f}, li = {0.f,0.f,0.f,0.f};
    for (int s = 0; s < NS; ++s) {
        const float* Pr = P + ((size_t)s * NTOK + t) * D2;
        float4 a = *(const float4*)&Pr[jr];
        float4 b = *(const float4*)&Pr[jr + 512];
        lr.x += a.x; lr.y += a.y; lr.z += a.z; lr.w += a.w;
        li.x += b.x; li.y += b.y; li.z += b.z; li.w += b.w;
    }
    float4 o;
    o.x = epi1(lr.x, li.x, hi);
    o.y = epi1(lr.y, li.y, hi);
    o.z = epi1(lr.z, li.z, hi);
    o.w = epi1(lr.w, li.w, hi);
    return o;
}

// z-writer: exactly epikv's cell branch (bx = it), NS partial slots
__device__ inline void d_zwrite(const float* __restrict__ P, int NS,
                                float* __restrict__ z, int t, int tid) {
#pragma unroll
    for (int it = 0; it < 2; ++it) {
        int j = it * 256 + tid;
        float lr = 0.f, li = 0.f;
        for (int s = 0; s < NS; ++s) {
            lr += P[((size_t)s * NTOK + t) * D2 + j];
            li += P[((size_t)s * NTOK + t) * D2 + DD + j];
        }
        float m = sqrtf(lr * lr + li * li + EPSF);
        float inv = 1.0f / (1.0f + m);
        z[(size_t)t * D2 + j]      = tanhf(lr * inv);
        z[(size_t)t * D2 + DD + j] = tanhf(li * inv);
    }
}

// kv combine: exactly epikv's doKV branch (bx-2 = it)
__device__ inline void d_kvcomb(const float* __restrict__ kvP,
                                const float* __restrict__ kb, const float* __restrict__ vb,
                                float* __restrict__ Kslot, float* __restrict__ Vslot,
                                int t, int tid) {
#pragma unroll
    for (int it = 0; it < 6; ++it) {
        int e = it * 256 + tid;
        float v = 0.f;
#pragma unroll
        for (int s = 0; s < 4; ++s)
            v += kvP[((size_t)s * NTOK + t) * 1536 + e];
        if (e < DD) Kslot[(size_t)t * DD + e]        = v + kb[e];
        else        Vslot[(size_t)t * D2 + (e - DD)] = v + vb[e - DD];
    }
}

// ================= verified GEMM body (64t x 64j, dbuf, 1 barrier/chunk) =====
__device__ __forceinline__ void d_gemmT(const float* __restrict__ WT,
                                        const float* __restrict__ X,
                                        float* __restrict__ P, int N,
                                        int j0, int t0, int k0, int NC, int slot,
                                        float* __restrict__ sX, float* __restrict__ sW) {
    constexpr int LDT = 68;
    int tid = threadIdx.x;
    int jq = tid & 15;
    int tq = tid >> 4;
    int f0 = tid * 2, f1 = tid * 2 + 1;
    int tA0 = f0 >> 3, kqA0 = f0 & 7;
    int tA1 = f1 >> 3, kqA1 = f1 & 7;
    int kwB0 = f0 >> 4, jB0 = f0 & 15;
    int kwB1 = f1 >> 4, jB1 = f1 & 15;
    float4 vx0, vx1, vw0, vw1;

#define GLOAD(kbase) do { \
        vx0 = *(const float4*)&X[(size_t)(t0 + tA0) * D2 + (kbase) + kqA0 * 4]; \
        vx1 = *(const float4*)&X[(size_t)(t0 + tA1) * D2 + (kbase) + kqA1 * 4]; \
        vw0 = *(const float4*)&WT[(size_t)((kbase) + kwB0) * N + j0 + jB0 * 4]; \
        vw1 = *(const float4*)&WT[(size_t)((kbase) + kwB1) * N + j0 + jB1 * 4]; \
    } while (0)
#define LSTORE(bufi) do { \
        float* sxB = sX + (bufi) * 2176; float* swB = sW + (bufi) * 2176; \
        sxB[(kqA0 * 4 + 0) * LDT + tA0] = vx0.x; \
        sxB[(kqA0 * 4 + 1) * LDT + tA0] = vx0.y; \
        sxB[(kqA0 * 4 + 2) * LDT + tA0] = vx0.z; \
        sxB[(kqA0 * 4 + 3) * LDT + tA0] = vx0.w; \
        sxB[(kqA1 * 4 + 0) * LDT + tA1] = vx1.x; \
        sxB[(kqA1 * 4 + 1) * LDT + tA1] = vx1.y; \
        sxB[(kqA1 * 4 + 2) * LDT + tA1] = vx1.z; \
        sxB[(kqA1 * 4 + 3) * LDT + tA1] = vx1.w; \
        *(float4*)&swB[kwB0 * LDT + jB0 * 4] = vw0; \
        *(float4*)&swB[kwB1 * LDT + jB1 * 4] = vw1; \
    } while (0)

    float4 acc0 = {0,0,0,0}, acc1 = {0,0,0,0}, acc2 = {0,0,0,0}, acc3 = {0,0,0,0};

    GLOAD(k0);
    LSTORE(0);
    __syncthreads();

    for (int kc = 0; kc < NC; ++kc) {
        if (kc + 1 < NC) GLOAD(k0 + (kc + 1) * 32);
        const float* sxB = sX + (kc & 1) * 2176;
        const float* swB = sW + (kc & 1) * 2176;
#pragma unroll 8
        for (int k = 0; k < 32; ++k) {
            float4 xa = *(const float4*)&sxB[k * LDT + tq * 4];
            float4 wb = *(const float4*)&swB[k * LDT + jq * 4];
            fma4(acc0, wb, xa.x);
            fma4(acc1, wb, xa.y);
            fma4(acc2, wb, xa.z);
            fma4(acc3, wb, xa.w);
        }
        if (kc + 1 < NC) LSTORE((kc + 1) & 1);
        __syncthreads();
    }
#undef GLOAD
#undef LSTORE

    size_t base = ((size_t)slot * NTOK + (t0 + tq * 4)) * N + j0 + jq * 4;
    *(float4*)&P[base]         = acc0;
    *(float4*)&P[base + N]     = acc1;
    *(float4*)&P[base + 2*N]   = acc2;
    *(float4*)&P[base + 3*N]   = acc3;
}

// GEMM body staging X from split-K partials (inline epilogue; bit-exact z values)
__device__ __forceinline__ void d_gemmP(const float* __restrict__ WT,
                                        const float* __restrict__ srcP, int NS,
                                        float* __restrict__ P, int N,
                                        int j0, int t0, int k0, int NC, int slot,
                                        float* __restrict__ sX, float* __restrict__ sW) {
    constexpr int LDT = 68;
    int tid = threadIdx.x;
    int jq = tid & 15;
    int tq = tid >> 4;
    int f0 = tid * 2, f1 = tid * 2 + 1;
    int tA0 = f0 >> 3, kqA0 = f0 & 7;
    int tA1 = f1 >> 3, kqA1 = f1 & 7;
    int kwB0 = f0 >> 4, jB0 = f0 & 15;
    int kwB1 = f1 >> 4, jB1 = f1 & 15;
    float4 vx0, vx1, vw0, vw1;

#define GLOADP(kbase) do { \
        vx0 = epi_load(srcP, NS, t0 + tA0, (kbase) + kqA0 * 4); \
        vx1 = epi_load(srcP, NS, t0 + tA1, (kbase) + kqA1 * 4); \
        vw0 = *(const float4*)&WT[(size_t)((kbase) + kwB0) * N + j0 + jB0 * 4]; \
        vw1 = *(const float4*)&WT[(size_t)((kbase) + kwB1) * N + j0 + jB1 * 4]; \
    } while (0)
#define LSTOREP(bufi) do { \
        float* sxB = sX + (bufi) * 2176; float* swB = sW + (bufi) * 2176; \
        sxB[(kqA0 * 4 + 0) * LDT + tA0] = vx0.x; \
        sxB[(kqA0 * 4 + 1) * LDT + tA0] = vx0.y; \
        sxB[(kqA0 * 4 + 2) * LDT + tA0] = vx0.z; \
        sxB[(kqA0 * 4 + 3) * LDT + tA0] = vx0.w; \
        sxB[(kqA1 * 4 + 0) * LDT + tA1] = vx1.x; \
        sxB[(kqA1 * 4 + 1) * LDT + tA1] = vx1.y; \
        sxB[(kqA1 * 4 + 2) * LDT + tA1] = vx1.z; \
        sxB[(kqA1 * 4 + 3) * LDT + tA1] = vx1.w; \
        *(float4*)&swB[kwB0 * LDT + jB0 * 4] = vw0; \
        *(float4*)&swB[kwB1 * LDT + jB1 * 4] = vw1; \
    } while (0)

    float4 acc0 = {0,0,0,0}, acc1 = {0,0,0,0}, acc2 = {0,0,0,0}, acc3 = {0,0,0,0};

    GLOADP(k0);
    LSTOREP(0);
    __syncthreads();

    for (int kc = 0; kc < NC; ++kc) {
        if (kc + 1 < NC) GLOADP(k0 + (kc + 1) * 32);
        const float* sxB = sX + (kc & 1) * 2176;
        const float* swB = sW + (kc & 1) * 2176;
#pragma unroll 8
        for (int k = 0; k < 32; ++k) {
            float4 xa = *(const float4*)&sxB[k * LDT + tq * 4];
            float4 wb = *(const float4*)&swB[k * LDT + jq * 4];
            fma4(acc0, wb, xa.x);
            fma4(acc1, wb, xa.y);
            fma4(acc2, wb, xa.z);
            fma4(acc3, wb, xa.w);
        }
        if (kc + 1 < NC) LSTOREP((kc + 1) & 1);
        __syncthreads();
    }
#undef GLOADP
#undef LSTOREP

    size_t base = ((size_t)slot * NTOK + (t0 + tq * 4)) * N + j0 + jq * 4;
    *(float4*)&P[base]         = acc0;
    *(float4*)&P[base + N]     = acc1;
    *(float4*)&P[base + 2*N]   = acc2;
    *(float4*)&P[base + 3*N]   = acc3;
}

// generic GEMM from z: grid (N/64, 4, S)
template<int KB>
__global__ __launch_bounds__(256) void gemmT_kernel(const float* __restrict__ WT,
                                                    const float* __restrict__ X,
                                                    float* __restrict__ P,
                                                    int N) {
    __shared__ __align__(16) float sX[2 * 2176];
    __shared__ __align__(16) float sW[2 * 2176];
    d_gemmT(WT, X, P, N, blockIdx.x * 64, blockIdx.y * 64,
            blockIdx.z * KB, KB / 32, blockIdx.z, sX, sW);
}

// generic GEMM from partials: grid (N/64, 4, S)
template<int KB>
__global__ __launch_bounds__(256) void gemmP_kernel(const float* __restrict__ WT,
                                                    const float* __restrict__ srcP, int NS,
                                                    float* __restrict__ P,
                                                    int N) {
    __shared__ __align__(16) float sX[2 * 2176];
    __shared__ __align__(16) float sW[2 * 2176];
    d_gemmP(WT, srcP, NS, P, N, blockIdx.x * 64, blockIdx.y * 64,
            blockIdx.z * KB, KB / 32, blockIdx.z, sX, sW);
}

// merged cell + KV gemm (both read the same X): flat grid 896 (round-7 verified)
__global__ __launch_bounds__(256) void cellkv_kernel(const float* __restrict__ CW,
                                                     const float* __restrict__ KVT,
                                                     const float* __restrict__ X,
                                                     float* __restrict__ cellP,
                                                     float* __restrict__ kvP) {
    __shared__ __align__(16) float sX[2 * 2176];
    __shared__ __align__(16) float sW[2 * 2176];
    int b = blockIdx.x;
    if (b < 512) {
        int s = b & 7, tile = b >> 3;
        int jx = tile & 15, tx = tile >> 4;
        d_gemmT(CW, X, cellP, D2, jx * 64, tx * 64, s * 128, 4, s, sX, sW);
    } else {
        int q = b - 512;
        int s = q & 3, tile = q >> 2;          // tile in [0,96)
        int jx = tile % 24, tx = tile / 24;
        d_gemmT(KVT, X, kvP, 1536, jx * 64, tx * 64, s * 256, 8, s, sX, sW);
    }
}

// d0: sym gemm staged from cellP4 (NS=4) + z-writer blocks. grid 512.
__global__ __launch_bounds__(256) void symepi_kernel(const float* __restrict__ symT,
                                                     const float* __restrict__ cellP4,
                                                     float* __restrict__ symP,
                                                     float* __restrict__ z) {
    __shared__ __align__(16) float sX[2 * 2176];
    __shared__ __align__(16) float sW[2 * 2176];
    int b = blockIdx.x;
    if (b < 256) {
        int jx = b & 7, tx = (b >> 3) & 3, s = b >> 5;
        d_gemmP(symT, cellP4, 4, symP, NSYM, jx * 64, tx * 64, s * 128, 4, s, sX, sW);
    } else {
        d_zwrite(cellP4, 4, z, b - 256, threadIdx.x);
    }
}

// d1-5 (big-ws): q gemm staged from cellP (NS=8) + z-writer + kvcomb. grid 768.
__global__ __launch_bounds__(256) void qepikv_kernel(const float* __restrict__ qwT,
                                                     const float* __restrict__ cellP,
                                                     const float* __restrict__ kvP,
                                                     const float* __restrict__ kb,
                                                     const float* __restrict__ vb,
                                                     float* __restrict__ QP,
                                                     float* __restrict__ z,
                                                     float* __restrict__ Kslot,
                                                     float* __restrict__ Vslot) {
    __shared__ __align__(16) float sX[2 * 2176];
    __shared__ __align__(16) float sW[2 * 2176];
    int b = blockIdx.x;
    if (b < 256) {
        int jx = b & 7, tx = (b >> 3) & 3, s = b >> 5;
        d_gemmP(qwT, cellP, 8, QP, DD, jx * 64, tx * 64, s * 128, 4, s, sX, sW);
    } else if (b < 512) {
        d_zwrite(cellP, 8, z, b - 256, threadIdx.x);
    } else {
        d_kvcomb(kvP, kb, vb, Kslot, Vslot, b - 512, threadIdx.x);
    }
}

// fallback: round-7 epikv
__global__ __launch_bounds__(256) void epikv_kernel(const float* __restrict__ cellP,
                                                    float* __restrict__ z,
                                                    const float* __restrict__ kvP,
                                                    const float* __restrict__ kb,
                                                    const float* __restrict__ vb,
                                                    float* __restrict__ Kslot,
                                                    float* __restrict__ Vslot,
                                                    int doKV) {
    int bx = blockIdx.x, t = blockIdx.y, tid = threadIdx.x;
    if (bx < 2) {
        int j = bx * 256 + tid;
        float lr = 0.f, li = 0.f;
#pragma unroll
        for (int s = 0; s < 8; ++s) {
            lr += cellP[((size_t)s * NTOK + t) * D2 + j];
            li += cellP[((size_t)s * NTOK + t) * D2 + DD + j];
        }
        float m = sqrtf(lr * lr + li * li + EPSF);
        float inv = 1.0f / (1.0f + m);
        z[(size_t)t * D2 + j]      = tanhf(lr * inv);
        z[(size_t)t * D2 + DD + j] = tanhf(li * inv);
    } else if (doKV) {
        int e = (bx - 2) * 256 + tid;
        float v = 0.f;
#pragma unroll
        for (int s = 0; s < 4; ++s)
            v += kvP[((size_t)s * NTOK + t) * 1536 + e];
        if (e < DD) Kslot[(size_t)t * DD + e]        = v + kb[e];
        else        Vslot[(size_t)t * D2 + (e - DD)] = v + vb[e - DD];
    }
}

// ---------------- attend: wave-shuffle reduce, softmax, ctx (8 QP partials) ----------------
__global__ __launch_bounds__(256) void attend8_kernel(float* __restrict__ z,
                                                      const float* __restrict__ QP,
                                                      const float* __restrict__ qb,
                                                      const float* __restrict__ Kmem,
                                                      const float* __restrict__ Vmem,
                                                      const float* __restrict__ conf,
                                                      int M) {
    int v = blockIdx.x, tid = threadIdx.x;
    int lane = tid & 63, w = tid >> 6;
    __shared__ float s_part[4][5];
    float q0 = 0.f, q1 = 0.f;
#pragma unroll
    for (int s = 0; s < 8; ++s) {
        q0 += QP[((size_t)s * NTOK + v) * DD + tid];
        q1 += QP[((size_t)s * NTOK + v) * DD + 256 + tid];
    }
    q0 += qb[tid];
    q1 += qb[256 + tid];
    float sc[5];
#pragma unroll
    for (int m = 0; m < 5; ++m) {
        if (m < M) {
            const float* K = Kmem + (size_t)m * NTOK * DD + (size_t)v * DD;
            sc[m] = q0 * K[tid] + q1 * K[256 + tid];
        } else sc[m] = 0.f;
    }
#pragma unroll
    for (int m = 0; m < 5; ++m) {
        if (m < M) {
            float x = wave_sum(sc[m]);
            if (lane == 0) s_part[w][m] = x;
        }
    }
    __syncthreads();
    float cf = conf[v];
    float scf[5];
    float mx = -1e30f;
#pragma unroll
    for (int m = 0; m < 5; ++m) {
        if (m < M) {
            float t = (s_part[0][m] + s_part[1][m] + s_part[2][m] + s_part[3][m]) * SCALE * cf;
            scf[m] = t;
            mx = fmaxf(mx, t);
        }
    }
    float sum = 0.f;
#pragma unroll
    for (int m = 0; m < 5; ++m) {
        if (m < M) { scf[m] = expf(scf[m] - mx); sum += scf[m]; }
    }
    float inv = 1.0f / sum;
#pragma unroll
    for (int r = 0; r < 4; ++r) {
        int e = r * 256 + tid;
        float ctx = 0.f;
#pragma unroll
        for (int m = 0; m < 5; ++m)
            if (m < M) ctx += scf[m] * Vmem[(size_t)m * NTOK * D2 + (size_t)v * D2 + e];
        z[(size_t)v * D2 + e] += 0.1f * ctx * inv;
    }
}

// ---------------- finish: wave-shuffle reductions, 512 threads (8 symP partials) -----
__global__ __launch_bounds__(512) void finish8_kernel(float* __restrict__ z,
                                                      const float* __restrict__ sym,
                                                      const float* __restrict__ snorm,
                                                      const float* __restrict__ con,
                                                      const float* __restrict__ conT,
                                                      const float* __restrict__ symP,
                                                      float* __restrict__ conf,
                                                      float* __restrict__ symErr,
                                                      float* __restrict__ conErr) {
    int t0 = blockIdx.x, tid = threadIdx.x;
    int lane = tid & 63, w = tid >> 6;
    __shared__ __align__(16) float s_z[D2];
    __shared__ float wA[8];
    __shared__ float wB[8]; __shared__ int wiB[8];
    __shared__ float wC[8], wD[8];
    __shared__ float wE[8];
    __shared__ int   s_ci[1];
    __shared__ float s_pd[512], s_pc[512];

    if (tid < 256) ((float4*)s_z)[tid] = ((const float4*)(z + (size_t)t0 * D2))[tid];
    __syncthreads();
    {
        float a = s_z[tid], b = s_z[512 + tid];
        float nrm = wave_sum(a * a + b * b);
        if (lane == 0) wA[w] = nrm;
    }
    __syncthreads();
    float znorm = 0.f;
#pragma unroll
    for (int k = 0; k < 8; ++k) znorm += wA[k];
    {
        float dot = 0.f;
#pragma unroll
        for (int s = 0; s < 8; ++s)
            dot += symP[((size_t)s * NTOK + t0) * NSYM + tid];
        float d = (znorm + snorm[tid]) - 2.f * dot;
        int idx = tid;
        wave_argmin(d, idx);
        if (lane == 0) { wB[w] = d; wiB[w] = idx; }
    }
    __syncthreads();
    float dmin = wB[0]; int si = wiB[0];
#pragma unroll
    for (int k = 1; k < 8; ++k) {
        if (wB[k] < dmin || (wB[k] == dmin && wiB[k] < si)) { dmin = wB[k]; si = wiB[k]; }
    }
    if (tid == 0) conf[t0] = 1.0f / (1.0f + dmin);
    {
        const float* crow = sym + (size_t)si * D2;
        float errp = 0.f, zn2 = 0.f;
#pragma unroll
        for (int r = 0; r < 2; ++r) {
            int e = r * 512 + tid;
            float zf = s_z[e];
            float diff = crow[e] - zf;
            errp += diff * diff;
            float zn = zf + diff;
            zn2 += zn * zn;
            s_z[e] = zn;
            z[(size_t)t0 * D2 + e] = zn;
        }
        errp = wave_sum(errp);
        zn2  = wave_sum(zn2);
        if (lane == 0) { wC[w] = errp; wD[w] = zn2; }
    }
    __syncthreads();
    if (tid == 0) {
        float s = 0.f;
#pragma unroll
        for (int k = 0; k < 8; ++k) s += wC[k];
        symErr[t0] += s;
    }
    float zsnorm = 0.f;
#pragma unroll
    for (int k = 0; k < 8; ++k) zsnorm += wD[k];
    {
        int c = tid & 63, sl = tid >> 6;
        float pd = 0.f, pc = 0.f;
        int kk0 = sl * 128;
#pragma unroll 4
        for (int k = kk0; k < kk0 + 128; ++k) {
            float wv = conT[(size_t)k * NCON + c];
            pd += wv * s_z[k];
            pc += wv * wv;
        }
        s_pd[tid] = pd; s_pc[tid] = pc;
    }
    __syncthreads();
    if (tid < 64) {
        float dot2 = 0.f, cn2 = 0.f;
#pragma unroll
        for (int i = 0; i < 8; ++i) { dot2 += s_pd[tid + 64 * i]; cn2 += s_pc[tid + 64 * i]; }
        float dc = (zsnorm + cn2) - 2.f * dot2;
        int ic = tid;
        wave_argmin(dc, ic);
        if (tid == 0) s_ci[0] = ic;
    }
    __syncthreads();
    int ci0 = s_ci[0];
    {
        const float* crow = con + (size_t)ci0 * D2;
        float p = 0.f;
#pragma unroll
        for (int r = 0; r < 2; ++r) {
            int e = r * 512 + tid;
            float diff = crow[e] - s_z[e];
            p += diff * diff;
        }
        p = wave_sum(p);
        if (lane == 0) wE[w] = p;
    }
    __syncthreads();
    if (tid == 0) {
        float s = 0.f;
#pragma unroll
        for (int k = 0; k < 8; ++k) s += wE[k];
        conErr[t0] += s;
    }
}

// ---------------- scatter (inline dec-combine) + hist + loss (last block) ----------------
__global__ __launch_bounds__(256) void scatterloss_kernel(const int* __restrict__ x,
                                                          const float* __restrict__ decP,
                                                          const float* __restrict__ db,
                                                          float* __restrict__ out,
                                                          const float* __restrict__ symErr,
                                                          const float* __restrict__ conErr) {
    int tid = threadIdx.x;
    if (blockIdx.x == BS_TOT / 4) {
        __shared__ int h[256];
        __shared__ double rs[256], rc[256];
        h[tid] = 0;
        __syncthreads();
        for (int i = tid; i < BS_TOT; i += 256) atomicAdd(&h[x[i]], 1);
        __syncthreads();
        rs[tid] = (double)h[tid] * (double)symErr[tid];
        rc[tid] = (double)h[tid] * (double)conErr[tid];
        __syncthreads();
        for (int off = 128; off > 0; off >>= 1) {
            if (tid < off) { rs[tid] += rs[tid + off]; rc[tid] += rc[tid + off]; }
            __syncthreads();
        }
        if (tid == 0) {
            const double denom = (double)BS_TOT * (double)D2;
            out[(size_t)BS_TOT * VOCAB]     = (float)(1.25 * rs[0] / denom);
            out[(size_t)BS_TOT * VOCAB + 1] = (float)(1.25 * rc[0] / denom);
        }
        return;
    }
    int pos = blockIdx.x * 4 + (tid >> 6);
    int lane = tid & 63;
    int v = x[pos];
    float4 a = {0.f, 0.f, 0.f, 0.f};
#pragma unroll
    for (int s = 0; s < 16; ++s) {
        float4 p = ((const float4*)&decP[((size_t)s * NTOK + v) * VOCAB])[lane];
        a.x += p.x; a.y += p.y; a.z += p.z; a.w += p.w;
    }
    float4 d4 = ((const float4*)db)[lane];
    a.x += d4.x; a.y += d4.y; a.z += d4.z; a.w += d4.w;
    ((float4*)(out + (size_t)pos * VOCAB))[lane] = a;
}

// ---------------- fused setup: 6 transposes + zero + buildcw + embed + symnorm ----------
// grid 3905, block 512 flat.
__global__ __launch_bounds__(512) void setup_kernel(const float* __restrict__ qw,
                                                    const float* __restrict__ kw,
                                                    const float* __restrict__ vw,
                                                    const float* __restrict__ sym,
                                                    const float* __restrict__ dec_w,
                                                    const float* __restrict__ con,
                                                    const float* __restrict__ Wr,
                                                    const float* __restrict__ Wi,
                                                    const float* __restrict__ mag,
                                                    const float* __restrict__ phase,
                                                    float* __restrict__ qwT,
                                                    float* __restrict__ KVT,
                                                    float* __restrict__ symT,
                                                    float* __restrict__ decT,
                                                    float* __restrict__ conT,
                                                    float* __restrict__ CW,
                                                    float* __restrict__ dst,
                                                    float* __restrict__ snorm,
                                                    float* __restrict__ symErr,
                                                    float* __restrict__ conErr) {
    __shared__ float t[32][33];
    __shared__ float tr[32][33], ti[32][33];
    __shared__ float s_w[8];
    int b = blockIdx.x;
    int tid = threadIdx.x;

    if (b < 2880) {   // transposes (all sources have 1024 columns)
        const float* in; float* outp; int ldo;
        if      (b < 512)  {           in = qw;    outp = qwT;      ldo = DD;    }
        else if (b < 1024) { b -= 512; in = kw;    outp = KVT;      ldo = 1536;  }
        else if (b < 2048) { b -= 1024; in = vw;   outp = KVT + DD; ldo = 1536;  }
        else if (b < 2560) { b -= 2048; in = sym;  outp = symT;     ldo = NSYM;  }
        else if (b < 2816) { b -= 2560; in = dec_w; outp = decT;    ldo = VOCAB; }
        else               { b -= 2816; in = con;  outp = conT;     ldo = NCON;  }
        int bx = b & 31, by = b >> 5;
        int c0 = bx * 32, r0 = by * 32;
        int xx = tid & 31, yy = tid >> 5;   // yy in 0..15
#pragma unroll
        for (int i = 0; i < 32; i += 16)
            t[yy + i][xx] = in[(size_t)(r0 + yy + i) * D2 + c0 + xx];
        __syncthreads();
#pragma unroll
        for (int i = 0; i < 32; i += 16)
            outp[(size_t)(c0 + yy + i) * ldo + r0 + xx] = t[xx][yy + i];
        return;
    }
    if (b == 2880) {
        if (tid < 256) { symErr[tid] = 0.f; conErr[tid] = 0.f; }
        return;
    }
    if (b < 3137) {   // buildcw, 256 blocks
        int q = b - 2881;
        int j0 = (q & 15) * 32, k0 = (q >> 4) * 32;
        int xx = tid & 31, yy = tid >> 5;
#pragma unroll
        for (int i = 0; i < 32; i += 16) {
            tr[yy + i][xx] = Wr[(size_t)(j0 + yy + i) * DD + k0 + xx];
            ti[yy + i][xx] = Wi[(size_t)(j0 + yy + i) * DD + k0 + xx];
        }
        __syncthreads();
#pragma unroll
        for (int i = 0; i < 32; i += 16) {
            float vr = tr[xx][yy + i];
            float vi = ti[xx][yy + i];
            int k = k0 + yy + i, j = j0 + xx;
            CW[(size_t)k * D2 + j]             = vr;
            CW[(size_t)k * D2 + DD + j]        = vi;
            CW[(size_t)(DD + k) * D2 + j]      = -vi;
            CW[(size_t)(DD + k) * D2 + DD + j] = vr;
        }
        return;
    }
    if (b < 3393) {   // embed, 256 blocks, 512 threads = 512 j
        int v = b - 3137, j = tid;
        float r = mag[v * DD + j], th = phase[v * DD + j];
        dst[(size_t)v * D2 + j]      = r * cosf(th);
        dst[(size_t)v * D2 + DD + j] = r * sinf(th);
        return;
    }
    {   // symnorm, 512 blocks
        int c = b - 3393;
        float2 vv = ((const float2*)(sym + (size_t)c * D2))[tid];
        float p = vv.x * vv.x + vv.y * vv.y;
        p = wave_sum(p);
        int lane = tid & 63, w = tid >> 6;
        if (lane == 0) s_w[w] = p;
        __syncthreads();
        if (tid == 0) {
            float s = 0.f;
#pragma unroll
            for (int k = 0; k < 8; ++k) s += s_w[k];
            snorm[c] = s;
        }
    }
}

// ---------------- host ----------------
extern "C" void kernel_launch(void* const* d_in, const int* in_sizes, int n_in,
                              void* d_out, int out_size, void* d_ws, size_t ws_size,
                              hipStream_t stream) {
    const int*   x     = (const int*)  d_in[0];
    const float* mag   = (const float*)d_in[1];
    const float* phase = (const float*)d_in[2];
    const float* Wr    = (const float*)d_in[3];
    const float* Wi    = (const float*)d_in[4];
    const float* qw    = (const float*)d_in[5];
    const float* qb    = (const float*)d_in[6];
    const float* kw    = (const float*)d_in[7];
    const float* kb    = (const float*)d_in[8];
    const float* vw    = (const float*)d_in[9];
    const float* vb    = (const float*)d_in[10];
    const float* dec_w = (const float*)d_in[11];
    const float* dec_b = (const float*)d_in[12];
    const float* sym   = (const float*)d_in[13];
    const float* con   = (const float*)d_in[14];
    float* out = (float*)d_out;

    // workspace layout (floats)
    float* ws     = (float*)d_ws;
    float* bufA   = ws;                          // 262144
    float* bufB   = bufA + NTOK * D2;            // 262144
    float* Kmem   = bufB + NTOK * D2;            // 786432
    float* Vmem   = Kmem + NDEPTH * NTOK * DD;   // 1572864
    float* rows   = Vmem + NDEPTH * NTOK * D2;   // 65536 (unused; layout keep)
    float* CW     = rows + NTOK * VOCAB;         // 1048576
    float* qwT    = CW + D2 * D2;                // 524288
    float* KVT    = qwT + D2 * DD;               // 1572864
    float* symT   = KVT + D2 * 1536;             // 524288
    float* decT   = symT + D2 * NSYM;            // 262144
    float* conT   = decT + D2 * VOCAB;           // 65536
    float* bigP   = conT + D2 * NCON;            // 2097152
    float* kvP    = bigP + 8 * NTOK * D2;        // 1572864
    float* snorm  = kvP + 4 * NTOK * 1536;       // 512
    float* conf   = snorm + NSYM;                // 256
    float* symErr = conf + NTOK;                 // 256
    float* conErr = symErr + NTOK;               // 256
    int*   hist   = (int*)(conErr + NTOK);       // 256 (unused; layout keep)
    float* QP2    = (float*)(hist + NTOK);       // 1048576 (big-ws only)

    size_t needed = ((size_t)(QP2 - ws) + 1048576) * sizeof(float);
    bool bigws = ws_size >= needed;

    float* halfA = bigP;                 // bigP[0 : 1M)
    float* halfB = bigP + 1048576;       // bigP[1M : 2M)

    setup_kernel<<<3905, 512, 0, stream>>>(qw, kw, vw, sym, dec_w, con, Wr, Wi, mag, phase,
                                           qwT, KVT, symT, decT, conT, CW,
                                           bufA, snorm, symErr, conErr);

    // ---------- d = 0 ----------
    gemmT_kernel<256><<<dim3(16, 4, 4), 256, 0, stream>>>(CW, bufA, halfA, D2);   // cellP4
    symepi_kernel<<<512, 256, 0, stream>>>(symT, halfA, halfB, bufB);             // symP=halfB, z->bufB
    finish8_kernel<<<NTOK, 512, 0, stream>>>(bufB, sym, snorm, con, conT, halfB,
                                             conf, symErr, conErr);
    float* cur = bufB;
    float* oth = bufA;

    // ---------- d = 1..5 ----------
    for (int d = 1; d < NDEPTH; ++d) {
        cellkv_kernel<<<896, 256, 0, stream>>>(CW, KVT, cur, bigP, kvP);
        if (bigws) {
            qepikv_kernel<<<768, 256, 0, stream>>>(qwT, bigP, kvP, kb, vb, QP2, oth,
                                                   Kmem + (size_t)(d - 1) * NTOK * DD,
                                                   Vmem + (size_t)(d - 1) * NTOK * D2);
            { float* t = cur; cur = oth; oth = t; }
            attend8_kernel<<<NTOK, 256, 0, stream>>>(cur, QP2, qb, Kmem, Vmem, conf, d);
        } else {
            epikv_kernel<<<dim3(8, 256), 256, 0, stream>>>(
                bigP, oth, kvP, kb, vb,
                Kmem + (size_t)(d - 1) * NTOK * DD,
                Vmem + (size_t)(d - 1) * NTOK * D2, 1);
            { float* t = cur; cur = oth; oth = t; }
            gemmT_kernel<128><<<dim3(8, 4, 8), 256, 0, stream>>>(qwT, cur, halfA, DD);
            attend8_kernel<<<NTOK, 256, 0, stream>>>(cur, halfA, qb, Kmem, Vmem, conf, d);
        }
        gemmT_kernel<128><<<dim3(8, 4, 8), 256, 0, stream>>>(symT, cur, halfA, NSYM);
        finish8_kernel<<<NTOK, 512, 0, stream>>>(cur, sym, snorm, con, conT, halfA,
                                                 conf, symErr, conErr);
    }

    // ---------- look iterations: z never materialized; partials ping-pong ----------
    gemmT_kernel<256><<<dim3(16, 4, 4), 256, 0, stream>>>(CW, cur, halfA, D2);        // look1
    gemmP_kernel<256><<<dim3(16, 4, 4), 256, 0, stream>>>(CW, halfA, 4, halfB, D2);   // look2
    gemmP_kernel<256><<<dim3(16, 4, 4), 256, 0, stream>>>(CW, halfB, 4, halfA, D2);   // look3

    // ---------- decode ----------
    gemmP_kernel<64><<<dim3(4, 4, 16), 256, 0, stream>>>(decT, halfA, 4, halfB, VOCAB);  // decP=halfB
    scatterloss_kernel<<<BS_TOT / 4 + 1, 256, 0, stream>>>(x, halfB, dec_b, out,
                                                           symErr, conErr);
}

// Round 9
// 580.359 us; speedup vs baseline: 1.1720x; 1.1720x over previous
//
#include <hip/hip_runtime.h>
#include <math.h>

// Problem constants
constexpr int DD    = 512;     // D
constexpr int D2    = 1024;    // 2D
constexpr int NTOK  = 256;     // vocab V (unique tokens = unique pipelines)
constexpr int NSYM  = 512;
constexpr int NCON  = 64;
constexpr int VOCAB = 256;
constexpr int BS_TOT = 32 * 512;   // B*S = 16384
constexpr int NDEPTH = 6;
constexpr int NLOOK  = 3;
constexpr float EPSF = 1e-8f;
constexpr float SCALE = 0.044194173824159216f; // 512^-0.5

__device__ inline void fma4(float4& a, const float4& w, float s) {
    a.x += w.x * s; a.y += w.y * s; a.z += w.z * s; a.w += w.w * s;
}

__device__ inline float wave_sum(float x) {
#pragma unroll
    for (int off = 32; off; off >>= 1) x += __shfl_xor(x, off, 64);
    return x;
}

__device__ inline void wave_argmin(float& d, int& i) {
#pragma unroll
    for (int off = 32; off; off >>= 1) {
        float od = __shfl_xor(d, off, 64);
        int   oi = __shfl_xor(i, off, 64);
        if (od < d || (od == d && oi < i)) { d = od; i = oi; }
    }
}

// ================= verified GEMM body (64t x 64j, dbuf, 1 barrier/chunk) =====
// X: [256][1024] t-major. WT: [1024][N] k-major. P[slot][256][N].
__device__ __forceinline__ void d_gemmT(const float* __restrict__ WT,
                                        const float* __restrict__ X,
                                        float* __restrict__ P, int N,
                                        int j0, int t0, int k0, int NC, int slot,
                                        float* __restrict__ sX, float* __restrict__ sW) {
    constexpr int LDT = 68;
    int tid = threadIdx.x;
    int jq = tid & 15;
    int tq = tid >> 4;
    int f0 = tid * 2, f1 = tid * 2 + 1;
    int tA0 = f0 >> 3, kqA0 = f0 & 7;
    int tA1 = f1 >> 3, kqA1 = f1 & 7;
    int kwB0 = f0 >> 4, jB0 = f0 & 15;
    int kwB1 = f1 >> 4, jB1 = f1 & 15;
    float4 vx0, vx1, vw0, vw1;

#define GLOAD(kbase) do { \
        vx0 = *(const float4*)&X[(size_t)(t0 + tA0) * D2 + (kbase) + kqA0 * 4]; \
        vx1 = *(const float4*)&X[(size_t)(t0 + tA1) * D2 + (kbase) + kqA1 * 4]; \
        vw0 = *(const float4*)&WT[(size_t)((kbase) + kwB0) * N + j0 + jB0 * 4]; \
        vw1 = *(const float4*)&WT[(size_t)((kbase) + kwB1) * N + j0 + jB1 * 4]; \
    } while (0)
#define LSTORE(bufi) do { \
        float* sxB = sX + (bufi) * 2176; float* swB = sW + (bufi) * 2176; \
        sxB[(kqA0 * 4 + 0) * LDT + tA0] = vx0.x; \
        sxB[(kqA0 * 4 + 1) * LDT + tA0] = vx0.y; \
        sxB[(kqA0 * 4 + 2) * LDT + tA0] = vx0.z; \
        sxB[(kqA0 * 4 + 3) * LDT + tA0] = vx0.w; \
        sxB[(kqA1 * 4 + 0) * LDT + tA1] = vx1.x; \
        sxB[(kqA1 * 4 + 1) * LDT + tA1] = vx1.y; \
        sxB[(kqA1 * 4 + 2) * LDT + tA1] = vx1.z; \
        sxB[(kqA1 * 4 + 3) * LDT + tA1] = vx1.w; \
        *(float4*)&swB[kwB0 * LDT + jB0 * 4] = vw0; \
        *(float4*)&swB[kwB1 * LDT + jB1 * 4] = vw1; \
    } while (0)

    float4 acc0 = {0,0,0,0}, acc1 = {0,0,0,0}, acc2 = {0,0,0,0}, acc3 = {0,0,0,0};

    GLOAD(k0);
    LSTORE(0);
    __syncthreads();

    for (int kc = 0; kc < NC; ++kc) {
        if (kc + 1 < NC) GLOAD(k0 + (kc + 1) * 32);
        const float* sxB = sX + (kc & 1) * 2176;
        const float* swB = sW + (kc & 1) * 2176;
#pragma unroll 8
        for (int k = 0; k < 32; ++k) {
            float4 xa = *(const float4*)&sxB[k * LDT + tq * 4];
            float4 wb = *(const float4*)&swB[k * LDT + jq * 4];
            fma4(acc0, wb, xa.x);
            fma4(acc1, wb, xa.y);
            fma4(acc2, wb, xa.z);
            fma4(acc3, wb, xa.w);
        }
        if (kc + 1 < NC) LSTORE((kc + 1) & 1);
        __syncthreads();
    }
#undef GLOAD
#undef LSTORE

    size_t base = ((size_t)slot * NTOK + (t0 + tq * 4)) * N + j0 + jq * 4;
    *(float4*)&P[base]         = acc0;
    *(float4*)&P[base + N]     = acc1;
    *(float4*)&P[base + 2*N]   = acc2;
    *(float4*)&P[base + 3*N]   = acc3;
}

// generic GEMM launch: grid (N/64, 4, S); K-slice = KB per z-slot
template<int KB>
__global__ __launch_bounds__(256) void gemmT_kernel(const float* __restrict__ WT,
                                                    const float* __restrict__ X,
                                                    float* __restrict__ P,
                                                    int N) {
    __shared__ __align__(16) float sX[2 * 2176];
    __shared__ __align__(16) float sW[2 * 2176];
    d_gemmT(WT, X, P, N, blockIdx.x * 64, blockIdx.y * 64,
            blockIdx.z * KB, KB / 32, blockIdx.z, sX, sW);
}

// merged cell + KV gemm (both read the same X): flat grid 896 (round-7 verified)
__global__ __launch_bounds__(256) void cellkv_kernel(const float* __restrict__ CW,
                                                     const float* __restrict__ KVT,
                                                     const float* __restrict__ X,
                                                     float* __restrict__ cellP,
                                                     float* __restrict__ kvP) {
    __shared__ __align__(16) float sX[2 * 2176];
    __shared__ __align__(16) float sW[2 * 2176];
    int b = blockIdx.x;
    if (b < 512) {
        int s = b & 7, tile = b >> 3;
        int jx = tile & 15, tx = tile >> 4;
        d_gemmT(CW, X, cellP, D2, jx * 64, tx * 64, s * 128, 4, s, sX, sW);
    } else {
        int q = b - 512;
        int s = q & 3, tile = q >> 2;          // tile in [0,96)
        int jx = tile % 24, tx = tile / 24;
        d_gemmT(KVT, X, kvP, 1536, jx * 64, tx * 64, s * 256, 8, s, sX, sW);
    }
}

// ---------------- merged cell epilogue (bx<2) + KV combine slot (bx>=2) ----------------
// grid (8, 256) with doKV=1, or (2,256) with doKV=0. block 256.
__global__ __launch_bounds__(256) void epikv_kernel(const float* __restrict__ cellP,
                                                    float* __restrict__ z,
                                                    const float* __restrict__ kvP,
                                                    const float* __restrict__ kb,
                                                    const float* __restrict__ vb,
                                                    float* __restrict__ Kslot,
                                                    float* __restrict__ Vslot,
                                                    int doKV) {
    int bx = blockIdx.x, t = blockIdx.y, tid = threadIdx.x;
    if (bx < 2) {
        int j = bx * 256 + tid;
        float lr = 0.f, li = 0.f;
#pragma unroll
        for (int s = 0; s < 8; ++s) {
            lr += cellP[((size_t)s * NTOK + t) * D2 + j];
            li += cellP[((size_t)s * NTOK + t) * D2 + DD + j];
        }
        float m = sqrtf(lr * lr + li * li + EPSF);
        float inv = 1.0f / (1.0f + m);
        z[(size_t)t * D2 + j]      = tanhf(lr * inv);
        z[(size_t)t * D2 + DD + j] = tanhf(li * inv);
    } else if (doKV) {
        int e = (bx - 2) * 256 + tid;
        float v = 0.f;
#pragma unroll
        for (int s = 0; s < 4; ++s)
            v += kvP[((size_t)s * NTOK + t) * 1536 + e];
        if (e < DD) Kslot[(size_t)t * DD + e]        = v + kb[e];
        else        Vslot[(size_t)t * D2 + (e - DD)] = v + vb[e - DD];
    }
}

// ---------------- attend: wave-shuffle reduce, softmax, ctx (8 QP partials) ----------------
__global__ __launch_bounds__(256) void attend8_kernel(float* __restrict__ z,
                                                      const float* __restrict__ QP,
                                                      const float* __restrict__ qb,
                                                      const float* __restrict__ Kmem,
                                                      const float* __restrict__ Vmem,
                                                      const float* __restrict__ conf,
                                                      int M) {
    int v = blockIdx.x, tid = threadIdx.x;
    int lane = tid & 63, w = tid >> 6;
    __shared__ float s_part[4][5];
    float q0 = 0.f, q1 = 0.f;
#pragma unroll
    for (int s = 0; s < 8; ++s) {
        q0 += QP[((size_t)s * NTOK + v) * DD + tid];
        q1 += QP[((size_t)s * NTOK + v) * DD + 256 + tid];
    }
    q0 += qb[tid];
    q1 += qb[256 + tid];
    float sc[5];
#pragma unroll
    for (int m = 0; m < 5; ++m) {
        if (m < M) {
            const float* K = Kmem + (size_t)m * NTOK * DD + (size_t)v * DD;
            sc[m] = q0 * K[tid] + q1 * K[256 + tid];
        } else sc[m] = 0.f;
    }
#pragma unroll
    for (int m = 0; m < 5; ++m) {
        if (m < M) {
            float x = wave_sum(sc[m]);
            if (lane == 0) s_part[w][m] = x;
        }
    }
    __syncthreads();
    float cf = conf[v];
    float scf[5];
    float mx = -1e30f;
#pragma unroll
    for (int m = 0; m < 5; ++m) {
        if (m < M) {
            float t = (s_part[0][m] + s_part[1][m] + s_part[2][m] + s_part[3][m]) * SCALE * cf;
            scf[m] = t;
            mx = fmaxf(mx, t);
        }
    }
    float sum = 0.f;
#pragma unroll
    for (int m = 0; m < 5; ++m) {
        if (m < M) { scf[m] = expf(scf[m] - mx); sum += scf[m]; }
    }
    float inv = 1.0f / sum;
#pragma unroll
    for (int r = 0; r < 4; ++r) {
        int e = r * 256 + tid;
        float ctx = 0.f;
#pragma unroll
        for (int m = 0; m < 5; ++m)
            if (m < M) ctx += scf[m] * Vmem[(size_t)m * NTOK * D2 + (size_t)v * D2 + e];
        z[(size_t)v * D2 + e] += 0.1f * ctx * inv;
    }
}

// ---------------- finish: wave-shuffle reductions, 512 threads (8 symP partials) -----
__global__ __launch_bounds__(512) void finish8_kernel(float* __restrict__ z,
                                                      const float* __restrict__ sym,
                                                      const float* __restrict__ snorm,
                                                      const float* __restrict__ con,
                                                      const float* __restrict__ conT,
                                                      const float* __restrict__ symP,
                                                      float* __restrict__ conf,
                                                      float* __restrict__ symErr,
                                                      float* __restrict__ conErr) {
    int t0 = blockIdx.x, tid = threadIdx.x;
    int lane = tid & 63, w = tid >> 6;
    __shared__ __align__(16) float s_z[D2];
    __shared__ float wA[8];
    __shared__ float wB[8]; __shared__ int wiB[8];
    __shared__ float wC[8], wD[8];
    __shared__ float wE[8];
    __shared__ int   s_ci[1];
    __shared__ float s_pd[512], s_pc[512];

    if (tid < 256) ((float4*)s_z)[tid] = ((const float4*)(z + (size_t)t0 * D2))[tid];
    __syncthreads();
    {
        float a = s_z[tid], b = s_z[512 + tid];
        float nrm = wave_sum(a * a + b * b);
        if (lane == 0) wA[w] = nrm;
    }
    __syncthreads();
    float znorm = 0.f;
#pragma unroll
    for (int k = 0; k < 8; ++k) znorm += wA[k];
    {
        float dot = 0.f;
#pragma unroll
        for (int s = 0; s < 8; ++s)
            dot += symP[((size_t)s * NTOK + t0) * NSYM + tid];
        float d = (znorm + snorm[tid]) - 2.f * dot;
        int idx = tid;
        wave_argmin(d, idx);
        if (lane == 0) { wB[w] = d; wiB[w] = idx; }
    }
    __syncthreads();
    float dmin = wB[0]; int si = wiB[0];
#pragma unroll
    for (int k = 1; k < 8; ++k) {
        if (wB[k] < dmin || (wB[k] == dmin && wiB[k] < si)) { dmin = wB[k]; si = wiB[k]; }
    }
    if (tid == 0) conf[t0] = 1.0f / (1.0f + dmin);
    {
        const float* crow = sym + (size_t)si * D2;
        float errp = 0.f, zn2 = 0.f;
#pragma unroll
        for (int r = 0; r < 2; ++r) {
            int e = r * 512 + tid;
            float zf = s_z[e];
            float diff = crow[e] - zf;
            errp += diff * diff;
            float zn = zf + diff;
            zn2 += zn * zn;
            s_z[e] = zn;
            z[(size_t)t0 * D2 + e] = zn;
        }
        errp = wave_sum(errp);
        zn2  = wave_sum(zn2);
        if (lane == 0) { wC[w] = errp; wD[w] = zn2; }
    }
    __syncthreads();
    if (tid == 0) {
        float s = 0.f;
#pragma unroll
        for (int k = 0; k < 8; ++k) s += wC[k];
        symErr[t0] += s;
    }
    float zsnorm = 0.f;
#pragma unroll
    for (int k = 0; k < 8; ++k) zsnorm += wD[k];
    {
        int c = tid & 63, sl = tid >> 6;
        float pd = 0.f, pc = 0.f;
        int kk0 = sl * 128;
#pragma unroll 4
        for (int k = kk0; k < kk0 + 128; ++k) {
            float wv = conT[(size_t)k * NCON + c];
            pd += wv * s_z[k];
            pc += wv * wv;
        }
        s_pd[tid] = pd; s_pc[tid] = pc;
    }
    __syncthreads();
    if (tid < 64) {
        float dot2 = 0.f, cn2 = 0.f;
#pragma unroll
        for (int i = 0; i < 8; ++i) { dot2 += s_pd[tid + 64 * i]; cn2 += s_pc[tid + 64 * i]; }
        float dc = (zsnorm + cn2) - 2.f * dot2;
        int ic = tid;
        wave_argmin(dc, ic);
        if (tid == 0) s_ci[0] = ic;
    }
    __syncthreads();
    int ci0 = s_ci[0];
    {
        const float* crow = con + (size_t)ci0 * D2;
        float p = 0.f;
#pragma unroll
        for (int r = 0; r < 2; ++r) {
            int e = r * 512 + tid;
            float diff = crow[e] - s_z[e];
            p += diff * diff;
        }
        p = wave_sum(p);
        if (lane == 0) wE[w] = p;
    }
    __syncthreads();
    if (tid == 0) {
        float s = 0.f;
#pragma unroll
        for (int k = 0; k < 8; ++k) s += wE[k];
        conErr[t0] += s;
    }
}

// ---------------- dec combine: rows = sum of 16 partials + dec_b ----------------
__global__ void deccomb_kernel(const float* __restrict__ P, const float* __restrict__ db,
                               float* __restrict__ rows) {
    int t = blockIdx.x, j = threadIdx.x;
    float v = 0.f;
#pragma unroll
    for (int s = 0; s < 16; ++s)
        v += P[((size_t)s * NTOK + t) * VOCAB + j];
    rows[(size_t)t * VOCAB + j] = v + db[j];
}

// ---------------- scatter + in-block hist + loss (last block) ----------------
__global__ __launch_bounds__(256) void scatterloss_kernel(const int* __restrict__ x,
                                                          const float* __restrict__ rows,
                                                          float* __restrict__ out,
                                                          const float* __restrict__ symErr,
                                                          const float* __restrict__ conErr) {
    int tid = threadIdx.x;
    if (blockIdx.x == BS_TOT / 4) {
        __shared__ int h[256];
        __shared__ double rs[256], rc[256];
        h[tid] = 0;
        __syncthreads();
        for (int i = tid; i < BS_TOT; i += 256) atomicAdd(&h[x[i]], 1);
        __syncthreads();
        rs[tid] = (double)h[tid] * (double)symErr[tid];
        rc[tid] = (double)h[tid] * (double)conErr[tid];
        __syncthreads();
        for (int off = 128; off > 0; off >>= 1) {
            if (tid < off) { rs[tid] += rs[tid + off]; rc[tid] += rc[tid + off]; }
            __syncthreads();
        }
        if (tid == 0) {
            const double denom = (double)BS_TOT * (double)D2;
            out[(size_t)BS_TOT * VOCAB]     = (float)(1.25 * rs[0] / denom);
            out[(size_t)BS_TOT * VOCAB + 1] = (float)(1.25 * rc[0] / denom);
        }
        return;
    }
    int pos = blockIdx.x * 4 + (tid >> 6);
    int lane = tid & 63;
    int v = x[pos];
    const float4* r = (const float4*)(rows + (size_t)v * VOCAB);
    ((float4*)(out + (size_t)pos * VOCAB))[lane] = r[lane];
}

// ---------------- fused setup: 6 transposes + zero + buildcw + embed + symnorm ----------
// grid 3905, block 512 flat.
__global__ __launch_bounds__(512) void setup_kernel(const float* __restrict__ qw,
                                                    const float* __restrict__ kw,
                                                    const float* __restrict__ vw,
                                                    const float* __restrict__ sym,
                                                    const float* __restrict__ dec_w,
                                                    const float* __restrict__ con,
                                                    const float* __restrict__ Wr,
                                                    const float* __restrict__ Wi,
                                                    const float* __restrict__ mag,
                                                    const float* __restrict__ phase,
                                                    float* __restrict__ qwT,
                                                    float* __restrict__ KVT,
                                                    float* __restrict__ symT,
                                                    float* __restrict__ decT,
                                                    float* __restrict__ conT,
                                                    float* __restrict__ CW,
                                                    float* __restrict__ dst,
                                                    float* __restrict__ snorm,
                                                    float* __restrict__ symErr,
                                                    float* __restrict__ conErr) {
    __shared__ float t[32][33];
    __shared__ float tr[32][33], ti[32][33];
    __shared__ float s_w[8];
    int b = blockIdx.x;
    int tid = threadIdx.x;

    if (b < 2880) {   // transposes (all sources have 1024 columns)
        const float* in; float* outp; int ldo;
        if      (b < 512)  {           in = qw;    outp = qwT;      ldo = DD;    }
        else if (b < 1024) { b -= 512; in = kw;    outp = KVT;      ldo = 1536;  }
        else if (b < 2048) { b -= 1024; in = vw;   outp = KVT + DD; ldo = 1536;  }
        else if (b < 2560) { b -= 2048; in = sym;  outp = symT;     ldo = NSYM;  }
        else if (b < 2816) { b -= 2560; in = dec_w; outp = decT;    ldo = VOCAB; }
        else               { b -= 2816; in = con;  outp = conT;     ldo = NCON;  }
        int bx = b & 31, by = b >> 5;
        int c0 = bx * 32, r0 = by * 32;
        int xx = tid & 31, yy = tid >> 5;   // yy in 0..15
#pragma unroll
        for (int i = 0; i < 32; i += 16)
            t[yy + i][xx] = in[(size_t)(r0 + yy + i) * D2 + c0 + xx];
        __syncthreads();
#pragma unroll
        for (int i = 0; i < 32; i += 16)
            outp[(size_t)(c0 + yy + i) * ldo + r0 + xx] = t[xx][yy + i];
        return;
    }
    if (b == 2880) {
        if (tid < 256) { symErr[tid] = 0.f; conErr[tid] = 0.f; }
        return;
    }
    if (b < 3137) {   // buildcw, 256 blocks
        int q = b - 2881;
        int j0 = (q & 15) * 32, k0 = (q >> 4) * 32;
        int xx = tid & 31, yy = tid >> 5;
#pragma unroll
        for (int i = 0; i < 32; i += 16) {
            tr[yy + i][xx] = Wr[(size_t)(j0 + yy + i) * DD + k0 + xx];
            ti[yy + i][xx] = Wi[(size_t)(j0 + yy + i) * DD + k0 + xx];
        }
        __syncthreads();
#pragma unroll
        for (int i = 0; i < 32; i += 16) {
            float vr = tr[xx][yy + i];
            float vi = ti[xx][yy + i];
            int k = k0 + yy + i, j = j0 + xx;
            CW[(size_t)k * D2 + j]             = vr;
            CW[(size_t)k * D2 + DD + j]        = vi;
            CW[(size_t)(DD + k) * D2 + j]      = -vi;
            CW[(size_t)(DD + k) * D2 + DD + j] = vr;
        }
        return;
    }
    if (b < 3393) {   // embed, 256 blocks, 512 threads = 512 j
        int v = b - 3137, j = tid;
        float r = mag[v * DD + j], th = phase[v * DD + j];
        dst[(size_t)v * D2 + j]      = r * cosf(th);
        dst[(size_t)v * D2 + DD + j] = r * sinf(th);
        return;
    }
    {   // symnorm, 512 blocks
        int c = b - 3393;
        float2 vv = ((const float2*)(sym + (size_t)c * D2))[tid];
        float p = vv.x * vv.x + vv.y * vv.y;
        p = wave_sum(p);
        int lane = tid & 63, w = tid >> 6;
        if (lane == 0) s_w[w] = p;
        __syncthreads();
        if (tid == 0) {
            float s = 0.f;
#pragma unroll
            for (int k = 0; k < 8; ++k) s += s_w[k];
            snorm[c] = s;
        }
    }
}

// ---------------- host ----------------
extern "C" void kernel_launch(void* const* d_in, const int* in_sizes, int n_in,
                              void* d_out, int out_size, void* d_ws, size_t ws_size,
                              hipStream_t stream) {
    const int*   x     = (const int*)  d_in[0];
    const float* mag   = (const float*)d_in[1];
    const float* phase = (const float*)d_in[2];
    const float* Wr    = (const float*)d_in[3];
    const float* Wi    = (const float*)d_in[4];
    const float* qw    = (const float*)d_in[5];
    const float* qb    = (const float*)d_in[6];
    const float* kw    = (const float*)d_in[7];
    const float* kb    = (const float*)d_in[8];
    const float* vw    = (const float*)d_in[9];
    const float* vb    = (const float*)d_in[10];
    const float* dec_w = (const float*)d_in[11];
    const float* dec_b = (const float*)d_in[12];
    const float* sym   = (const float*)d_in[13];
    const float* con   = (const float*)d_in[14];
    float* out = (float*)d_out;

    // workspace layout (floats); total ~42.5 MB
    float* ws     = (float*)d_ws;
    float* bufA   = ws;                          // 262144
    float* bufB   = bufA + NTOK * D2;            // 262144
    float* Kmem   = bufB + NTOK * D2;            // 786432
    float* Vmem   = Kmem + NDEPTH * NTOK * DD;   // 1572864
    float* rows   = Vmem + NDEPTH * NTOK * D2;   // 65536
    float* CW     = rows + NTOK * VOCAB;         // 1048576
    float* qwT    = CW + D2 * D2;                // 524288
    float* KVT    = qwT + D2 * DD;               // 1572864
    float* symT   = KVT + D2 * 1536;             // 524288
    float* decT   = symT + D2 * NSYM;            // 262144
    float* conT   = decT + D2 * VOCAB;           // 65536
    float* bigP   = conT + D2 * NCON;            // 2097152
    float* kvP    = bigP + 8 * NTOK * D2;        // 1572864
    float* snorm  = kvP + 4 * NTOK * 1536;       // 512
    float* conf   = snorm + NSYM;                // 256
    float* symErr = conf + NTOK;                 // 256
    float* conErr = symErr + NTOK;               // 256

    float* QP   = bigP;                 // 8*256*512
    float* symP = bigP + 1048576;       // 8*256*512
    float* decP = bigP;                 // 16*256*256

    setup_kernel<<<3905, 512, 0, stream>>>(qw, kw, vw, sym, dec_w, con, Wr, Wi, mag, phase,
                                           qwT, KVT, symT, decT, conT, CW,
                                           bufA, snorm, symErr, conErr);

    float* cur = bufA;
    float* oth = bufB;
    for (int d = 0; d < NDEPTH; ++d) {
        if (d == 0) {
            gemmT_kernel<128><<<dim3(16, 4, 8), 256, 0, stream>>>(CW, cur, bigP, D2);
            epikv_kernel<<<dim3(2, 256), 256, 0, stream>>>(bigP, oth, kvP, kb, vb,
                                                           Kmem, Vmem, 0);
        } else {
            // cell(d) + KV(slot d-1) share the same input `cur`
            cellkv_kernel<<<896, 256, 0, stream>>>(CW, KVT, cur, bigP, kvP);
            epikv_kernel<<<dim3(8, 256), 256, 0, stream>>>(
                bigP, oth, kvP, kb, vb,
                Kmem + (size_t)(d - 1) * NTOK * DD,
                Vmem + (size_t)(d - 1) * NTOK * D2, 1);
        }
        { float* t = cur; cur = oth; oth = t; }
        if (d > 0) {
            gemmT_kernel<128><<<dim3(8, 4, 8), 256, 0, stream>>>(qwT, cur, QP, DD);
            attend8_kernel<<<NTOK, 256, 0, stream>>>(cur, QP, qb, Kmem, Vmem, conf, d);
        }
        gemmT_kernel<128><<<dim3(8, 4, 8), 256, 0, stream>>>(symT, cur, symP, NSYM);
        finish8_kernel<<<NTOK, 512, 0, stream>>>(cur, sym, snorm, con, conT, symP,
                                                 conf, symErr, conErr);
    }
    for (int l = 0; l < NLOOK; ++l) {
        gemmT_kernel<128><<<dim3(16, 4, 8), 256, 0, stream>>>(CW, cur, bigP, D2);
        epikv_kernel<<<dim3(2, 256), 256, 0, stream>>>(bigP, oth, kvP, kb, vb,
                                                       Kmem, Vmem, 0);
        { float* t = cur; cur = oth; oth = t; }
    }
    gemmT_kernel<64><<<dim3(4, 4, 16), 256, 0, stream>>>(decT, cur, decP, VOCAB);
    deccomb_kernel<<<256, 256, 0, stream>>>(decP, dec_b, rows);
    scatterloss_kernel<<<BS_TOT / 4 + 1, 256, 0, stream>>>(x, rows, out, symErr, conErr);
}